// Round 10
// baseline (293.621 us; speedup 1.0000x reference)
//
#include <hip/hip_runtime.h>
#include <hip/hip_fp16.h>

#define BATCH 65536
#define KDIM  784
#define HID   512
#define BM    64
#define XB    1056          // x LDS block stride: 1024B block + 32B pad (bank stagger)
#define XCH   (16 * XB)     // one k=128 chunk: 16 blocks (4 bg x 4 ktl) = 16896 B

typedef float    f32x4 __attribute__((ext_vector_type(4)));
typedef _Float16 f16x8 __attribute__((ext_vector_type(8)));
typedef _Float16 f16x4 __attribute__((ext_vector_type(4)));

// W1 (784x512 fp32) -> ws: fp16 in exact A-fragment order [net][kt][hid][32],
// zero-padded to k=800. Consumed global(L2)->reg.
__global__ void prep_w1_kernel(const float* __restrict__ W1_0,
                               const float* __restrict__ W1_1,
                               _Float16* __restrict__ wsB) {
  int i = blockIdx.x * 256 + threadIdx.x;       // [0, 2*800*512)
  if (i >= 2 * 800 * 512) return;
  int net = i / (800 * 512);
  int rem = i - net * (800 * 512);
  int k = rem >> 9;        // 0..799
  int hid = rem & 511;
  const float* W = net ? W1_1 : W1_0;
  float v = (k < KDIM) ? W[k * 512 + hid] : 0.f;
  int kt = k >> 5, kk = k & 31;
  wsB[(((size_t)(net * 25 + kt) * HID + hid) << 5) + kk] = (_Float16)v;
}

// W2 (512x10 fp32) -> ws: fp16 W2^T padded to 16 rows, [net][16][512], linear.
__global__ void prep_w2_kernel(const float* __restrict__ W2_0,
                               const float* __restrict__ W2_1,
                               _Float16* __restrict__ wsW2) {
  int i = blockIdx.x * 256 + threadIdx.x;       // [0, 2*16*512)
  if (i >= 2 * 16 * 512) return;
  int net = i >> 13;
  int rem = i & 8191;
  int li = rem >> 9;       // logit row 0..15
  int k = rem & 511;
  const float* W = net ? W2_1 : W2_0;
  wsW2[i] = (_Float16)((li < 10) ? W[k * 10 + li] : 0.f);
}

__launch_bounds__(1024, 4)
__global__ void fused_mlp_kernel(const float* __restrict__ x,
                                 const float* __restrict__ b1_0,
                                 const float* __restrict__ b2_0,
                                 const float* __restrict__ b1_1,
                                 const float* __restrict__ b2_1,
                                 const _Float16* __restrict__ wsB,
                                 const _Float16* __restrict__ wsW2,
                                 float* __restrict__ out) {
  // region: x double-buffer (2 x 16896B fragment-block chunks) during GEMM1;
  // then h[64][1024B f16] (full 64KB); then outb.
  __shared__ __attribute__((aligned(16))) char region[65536];
  __shared__ float pbuf[2][BM * 11];

  char* bufA = region;
  char* bufB = region + XCH;

  const int t    = threadIdx.x;
  const int lane = t & 63;
  const int wid  = t >> 6;            // 0..15
  const int l15  = lane & 15;
  const int l4   = lane >> 4;
  const int hid0 = (wid & 7) << 6;    // wave owns hid [hid0, hid0+64)
  const int bg0  = (wid >> 3) << 1;   // wave owns batch groups bg0, bg0+1 (16 rows each)
  const int row0 = blockIdx.x * BM;

  // stage geometry: thread t -> rows {sr, sr+32}, k-slot su (16B contiguous per lane)
  const int sr   = t >> 5;            // 0..31
  const int su   = t & 31;
  const int sktl = su >> 3;           // k-tile within chunk
  const int sl4  = (su >> 1) & 3;     // fragment l4
  const int soff = (su & 1) << 3;     // 8B half of 16B slot

  for (int net = 0; net < 2; ++net) {
    const float* xb = x + (size_t)net * BATCH * KDIM + (size_t)row0 * KDIM;
    const _Float16* wnet = wsB + (size_t)net * 25 * HID * 32;
    const float* b1 = net ? b1_1 : b1_0;
    const float* b2 = net ? b2_1 : b2_0;

    f32x4 acc[4][2];
#pragma unroll
    for (int rf = 0; rf < 4; ++rf)
#pragma unroll
      for (int nf = 0; nf < 2; ++nf) acc[rf][nf] = (f32x4){0.f, 0.f, 0.f, 0.f};

    f32x4 xr0, xr1;                   // in-flight stage data (8 VGPR)

    auto cvt4 = [](f32x4 a) {
      f16x4 r;
      r[0] = (_Float16)a[0]; r[1] = (_Float16)a[1];
      r[2] = (_Float16)a[2]; r[3] = (_Float16)a[3];
      return r;
    };
    // lane-contiguous loads: each instr = 2 rows x 512B fully covered
    auto load_chunk = [&](int c) {
      const float* src = xb + (size_t)sr * KDIM + (c << 7) + (su << 2);
      xr0 = *(const f32x4*)src;
      xr1 = *(const f32x4*)(src + (size_t)32 * KDIM);
    };
    // fragment-block scatter: block(bg,ktl) at (bg*4+ktl)*XB, slot = l15*4+l4
    auto write_chunk = [&](char* buf) {
      int r1 = sr, r2 = sr + 32;
      *(f16x4*)(buf + (((r1 >> 4) << 2) + sktl) * XB +
                ((((r1 & 15) << 2) + sl4) << 4) + soff) = cvt4(xr0);
      *(f16x4*)(buf + (((r2 >> 4) << 2) + sktl) * XB +
                ((((r2 & 15) << 2) + sl4) << 4) + soff) = cvt4(xr1);
    };
    auto load_tail = [&]() {          // kt24: k 768..783 real
      if (t < 256) {
        int r = t >> 2, v = t & 3;
        xr0 = *(const f32x4*)(xb + (size_t)r * KDIM + 768 + (v << 2));
      }
    };
    auto write_tail = [&]() {         // into bufA, ktl=0 blocks; l4 2..3 zeroed
      if (t < 256) {
        int r = t >> 2, v = t & 3;
        *(f16x4*)(bufA + ((r >> 4) << 2) * XB +
                  ((((r & 15) << 2) + (v >> 1)) << 4) + ((v & 1) << 3)) = cvt4(xr0);
      } else if (t < 512) {
        int t2 = t - 256;
        int r = t2 >> 2, v = t2 & 3;
        *(f16x4*)(bufA + ((r >> 4) << 2) * XB +
                  ((((r & 15) << 2) + 2 + (v >> 1)) << 4) + ((v & 1) << 3)) =
            (f16x4){(_Float16)0.f, (_Float16)0.f, (_Float16)0.f, (_Float16)0.f};
      }
    };
    // 4 K-tiles of a chunk: W1 frags L2->reg, x frags ds_read_b128 (2 lanes/bank)
    auto compute4 = [&](const char* xl, int kt0) {
#pragma unroll 2
      for (int ktl = 0; ktl < 4; ++ktl) {
        const _Float16* wk = wnet + (((size_t)(kt0 + ktl) * HID) << 5);
        f16x8 bw[4];
#pragma unroll
        for (int rf = 0; rf < 4; ++rf)
          bw[rf] = *(const f16x8*)(wk + ((hid0 + (rf << 4) + l15) << 5) + (l4 << 3));
#pragma unroll
        for (int nf = 0; nf < 2; ++nf) {
          int bg = bg0 + nf;
          f16x8 bx = *(const f16x8*)(xl + ((bg << 2) + ktl) * XB +
                                     (((l15 << 2) + l4) << 4));
#pragma unroll
          for (int rf = 0; rf < 4; ++rf)
            acc[rf][nf] = __builtin_amdgcn_mfma_f32_16x16x32_f16(bw[rf], bx, acc[rf][nf], 0, 0, 0);
        }
      }
    };
    auto compute_tail = [&]() {       // kt 24 (bufA, ktl=0; upper k zeroed both sides)
      const _Float16* wk = wnet + (((size_t)24 * HID) << 5);
      f16x8 bw[4];
#pragma unroll
      for (int rf = 0; rf < 4; ++rf)
        bw[rf] = *(const f16x8*)(wk + ((hid0 + (rf << 4) + l15) << 5) + (l4 << 3));
#pragma unroll
      for (int nf = 0; nf < 2; ++nf) {
        int bg = bg0 + nf;
        f16x8 bx = *(const f16x8*)(bufA + (bg << 2) * XB + (((l15 << 2) + l4) << 4));
#pragma unroll
        for (int rf = 0; rf < 4; ++rf)
          acc[rf][nf] = __builtin_amdgcn_mfma_f32_16x16x32_f16(bw[rf], bx, acc[rf][nf], 0, 0, 0);
      }
    };

    // ---- chunk pipeline: loads(c+1) issued first, ds_write after compute(c) ----
    load_chunk(0); write_chunk(bufA); __syncthreads();
    load_chunk(1); compute4(bufA, 0);  write_chunk(bufB); __syncthreads();
    load_chunk(2); compute4(bufB, 4);  write_chunk(bufA); __syncthreads();
    load_chunk(3); compute4(bufA, 8);  write_chunk(bufB); __syncthreads();
    load_chunk(4); compute4(bufB, 12); write_chunk(bufA); __syncthreads();
    load_chunk(5); compute4(bufA, 16); write_chunk(bufB); __syncthreads();
    load_tail();   compute4(bufB, 20); write_tail();      __syncthreads();
    compute_tail();
    __syncthreads();   // x fully consumed; region becomes h

    // ---- publish h: bias+relu+cvt; h[b] at region + b*1024, swizzled slots ----
#pragma unroll
    for (int rf = 0; rf < 4; ++rf) {
      f32x4 b1v = *(const f32x4*)(b1 + hid0 + (rf << 4) + (l4 << 2));
#pragma unroll
      for (int nf = 0; nf < 2; ++nf) {
        f16x4 hv;
#pragma unroll
        for (int j = 0; j < 4; ++j)
          hv[j] = (_Float16)fmaxf(acc[rf][nf][j] + b1v[j], 0.f);
        int b  = ((bg0 + nf) << 4) + l15;
        int hl = hid0 + (rf << 4) + (l4 << 2);
        int sp = (hl >> 3) ^ (b & 7);
        *(f16x4*)(region + (b << 10) + (sp << 4) + ((hl & 4) << 1)) = hv;
      }
    }
    __syncthreads();

    // ---- GEMM2 (waves 0..3): logits^T(16x16) per wave over k=512 ----
    if (wid < 4) {
      f32x4 l2 = {0.f, 0.f, 0.f, 0.f};
      const _Float16* w2n = wsW2 + (((net << 4) + l15) << 9);  // A row = logit = l15
      int b = (wid << 4) + l15;                                // B col = batch row
#pragma unroll
      for (int kk = 0; kk < 16; ++kk) {
        f16x8 aw = *(const f16x8*)(w2n + (kk << 5) + (l4 << 3));
        f16x8 bh = *(const f16x8*)(region + (b << 10) +
                                   ((((kk << 2) + l4) ^ (b & 7)) << 4));
        l2 = __builtin_amdgcn_mfma_f32_16x16x32_f16(aw, bh, l2, 0, 0, 0);
      }
      // softmax: lane holds logits cls0..cls0+3 of batch row b
      int cls0 = l4 << 2;
      float lg[4];
#pragma unroll
      for (int j = 0; j < 4; ++j) {
        int c = cls0 + j;
        lg[j] = (c < 10) ? (l2[j] + b2[c]) : -1e30f;
      }
      float mx = fmaxf(fmaxf(lg[0], lg[1]), fmaxf(lg[2], lg[3]));
      mx = fmaxf(mx, __shfl_xor(mx, 16));
      mx = fmaxf(mx, __shfl_xor(mx, 32));
      float ev[4], sum = 0.f;
#pragma unroll
      for (int j = 0; j < 4; ++j) {
        ev[j] = (cls0 + j < 10) ? __expf(lg[j] - mx) : 0.f;
        sum += ev[j];
      }
      sum += __shfl_xor(sum, 16);
      sum += __shfl_xor(sum, 32);
      float inv = 1.f / sum;
#pragma unroll
      for (int j = 0; j < 4; ++j) {
        int c = cls0 + j;
        if (c < 10) pbuf[net][b * 11 + c] = ev[j] * inv;
      }
    }
    __syncthreads();   // pbuf visible; region free for next net
  } // net

  // ---- out[n][s] = sum_{a+c=s} p0[n][a] * p1[n][c] ----
  float* outb = (float*)region;
  {
    int r  = t & 63;
    int sq = t >> 6;                  // 16 squads x 2 s-values (covers 0..31)
#pragma unroll
    for (int si = 0; si < 2; ++si) {
      int s = sq * 2 + si;
      if (s < 19) {
        int alo = (s > 9) ? (s - 9) : 0;
        int ahi = (s < 9) ? s : 9;
        float a = 0.f;
        for (int aa = alo; aa <= ahi; ++aa)
          a += pbuf[0][r * 11 + aa] * pbuf[1][r * 11 + (s - aa)];
        outb[r * 19 + s] = a;
      }
    }
  }
  __syncthreads();
  {
    float* og = out + (size_t)row0 * 19;
    for (int i = t; i < BM * 19; i += 1024) og[i] = outb[i];
  }
}

extern "C" void kernel_launch(void* const* d_in, const int* in_sizes, int n_in,
                              void* d_out, int out_size, void* d_ws, size_t ws_size,
                              hipStream_t stream) {
  (void)in_sizes; (void)n_in; (void)out_size; (void)ws_size;
  const float* x    = (const float*)d_in[0];
  const float* W1_0 = (const float*)d_in[1];
  const float* b1_0 = (const float*)d_in[2];
  const float* W2_0 = (const float*)d_in[3];
  const float* b2_0 = (const float*)d_in[4];
  const float* W1_1 = (const float*)d_in[5];
  const float* b1_1 = (const float*)d_in[6];
  const float* W2_1 = (const float*)d_in[7];
  const float* b2_1 = (const float*)d_in[8];
  float* out = (float*)d_out;

  _Float16* wsB  = (_Float16*)d_ws;                 // 2*25*512*32 f16 = 1.6 MB
  _Float16* wsW2 = wsB + 2 * 25 * HID * 32;         // 2*16*512 f16 = 32 KB

  hipLaunchKernelGGL(prep_w1_kernel, dim3(3200), dim3(256), 0, stream, W1_0, W1_1, wsB);
  hipLaunchKernelGGL(prep_w2_kernel, dim3(64), dim3(256), 0, stream, W2_0, W2_1, wsW2);
  hipLaunchKernelGGL(fused_mlp_kernel, dim3(BATCH / BM), dim3(1024), 0, stream,
                     x, b1_0, b2_0, b1_1, b2_1, wsB, wsW2, out);
}